// Round 1
// 1080.148 us; speedup vs baseline: 1.1559x; 1.1559x over previous
//
#include <hip/hip_runtime.h>
#include <stdint.h>
#include <stddef.h>

typedef __attribute__((ext_vector_type(8))) short short8;
typedef __attribute__((ext_vector_type(4))) short short4v;
typedef __attribute__((ext_vector_type(4))) float floatx4;

__device__ __forceinline__ short f2bf(float f) {
    union { float f; uint32_t u; } v; v.f = f;
    uint32_t u = v.u + 0x7fffu + ((v.u >> 16) & 1u);
    return (short)(u >> 16);
}

__device__ __forceinline__ void async16(short* lds, const short* g) {
    __builtin_amdgcn_global_load_lds(
        (const __attribute__((address_space(1))) unsigned int*)g,
        (__attribute__((address_space(3))) unsigned int*)lds, 16, 0, 0);
}

// stage a 128-row x 32-col bf16 tile into LDS (row-major, no pad — lane-ordered for global_load_lds)
// src points at (row0, k0); ld = row stride in elements. Each thread moves 2x16B.
__device__ __forceinline__ void stage128x32(short* lds, const short* src, size_t ld, int t) {
    const short* g = src + (size_t)(t >> 2) * ld + (t & 3) * 8;
    async16(lds + t * 8, g);
    async16(lds + 2048 + t * 8, g + 64 * ld);
}

// ---------------- fp32 -> bf16 cast ----------------
__global__ __launch_bounds__(256) void cast_kernel(const float* __restrict__ src,
                                                   short* __restrict__ dst, int n4) {
    int i = blockIdx.x * blockDim.x + threadIdx.x;
    if (i < n4) {
        float4 v = ((const float4*)src)[i];
        short4v o;
        o.x = f2bf(v.x); o.y = f2bf(v.y); o.z = f2bf(v.z); o.w = f2bf(v.w);
        ((short4v*)dst)[i] = o;
    }
}

// ---------------- projection GEMM: Y = X @ W^T + b (dual store: Y and Yt) ----------------
// A: (M,768) bf16, W: (768,768) bf16 row-major (B[n][k]). M = 64*L, exact 128-tiles.
__global__ __launch_bounds__(256) void proj_gemm(
    const short* __restrict__ A, const short* __restrict__ W,
    const float* __restrict__ bias,
    short* __restrict__ Y, short* __restrict__ Yt, int L)
{
    __shared__ short As[4096], Bs[4096];
    const int t = threadIdx.x, w = t >> 6, l = t & 63;
    const int wr = (w >> 1) * 64, wc = (w & 1) * 64, lr = l & 15, lq = l >> 4;
    const size_t m0 = (size_t)blockIdx.x * 128;
    const int n0 = blockIdx.y * 128;
    const short* Ab = A + m0 * 768;
    const short* Bb = W + (size_t)n0 * 768;

    floatx4 acc[4][4];
#pragma unroll
    for (int i = 0; i < 4; ++i)
#pragma unroll
        for (int j = 0; j < 4; ++j) acc[i][j] = (floatx4){0.f, 0.f, 0.f, 0.f};

    for (int k0 = 0; k0 < 768; k0 += 32) {
        stage128x32(As, Ab + k0, 768, t);
        stage128x32(Bs, Bb + k0, 768, t);
        __syncthreads();
        short8 af[4], bf[4];
#pragma unroll
        for (int i = 0; i < 4; ++i) af[i] = *(const short8*)(As + (wr + i * 16 + lr) * 32 + lq * 8);
#pragma unroll
        for (int j = 0; j < 4; ++j) bf[j] = *(const short8*)(Bs + (wc + j * 16 + lr) * 32 + lq * 8);
#pragma unroll
        for (int i = 0; i < 4; ++i)
#pragma unroll
            for (int j = 0; j < 4; ++j)
                acc[i][j] = __builtin_amdgcn_mfma_f32_16x16x32_bf16(af[i], bf[j], acc[i][j], 0, 0, 0);
        __syncthreads();
    }

#pragma unroll
    for (int i = 0; i < 4; ++i) {
        const int mb = (int)m0 + wr + i * 16 + lq * 4;
        const int b_ = mb / L, pos = mb - b_ * L;
#pragma unroll
        for (int j = 0; j < 4; ++j) {
            const int n = n0 + wc + j * 16 + lr;
            const float bv = bias[n];
            short4v tv;
#pragma unroll
            for (int r2 = 0; r2 < 4; ++r2) {
                short hv = f2bf(acc[i][j][r2] + bv);
                Y[(size_t)(mb + r2) * 768 + n] = hv;
                tv[r2] = hv;
            }
            *(short4v*)(Yt + ((size_t)b_ * 768 + n) * L + pos) = tv;
        }
    }
}

// ---------------- fused S GEMM + mask bias + row softmax -> P bf16 ----------------
// One block: 64 Q-rows x full C for one (batch, pair). 8 waves = 2 row-waves x 4 col-waves.
// S never leaves registers. Cross-wave row reduce via small LDS array.
// Two pairs (sharing the same K matrix and mask) are handled via blockIdx.y.
template<int C>
__global__ __launch_bounds__(512) void fused_sp(
    const short* __restrict__ K,     // (64, C, 768) bf16
    const float* __restrict__ mask,  // (64, C)
    const short* __restrict__ Q0, int R0, short* __restrict__ P0,
    const short* __restrict__ Q1, int R1, short* __restrict__ P1)
{
    constexpr int NT = C / 16;       // 16-col tiles in C
    constexpr int NTW = NT / 4;      // tiles per col-wave (9 / 5 / 3)
    __shared__ short Ks[C * 32];     // C x 32 k-slice
    __shared__ short Qs[64 * 32];    // 64 x 32 k-slice
    __shared__ float red[4][64];     // cross-wave row reduce

    const int t = threadIdx.x, w = t >> 6, l = t & 63;
    const int wr2 = w >> 2;          // 0..1  (row-wave: rows wr2*32..+31)
    const int wc  = w & 3;           // 0..3  (col-wave: tiles wc*NTW..)
    const int lr = l & 15, lq = l >> 4;

    const int b  = blockIdx.z;
    const int pr = blockIdx.y;
    const int R  = pr ? R1 : R0;
    const int m0 = blockIdx.x * 64;
    if (m0 >= R) return;             // flattened-pair guard (block-uniform)

    const short* Qb = (pr ? Q1 : Q0) + ((size_t)b * R + m0) * 768;
    short*       Pb = (pr ? P1 : P0) + ((size_t)b * R + m0) * C;
    const short* Kb = K + (size_t)b * C * 768;

    floatx4 acc[2][NTW];
#pragma unroll
    for (int i = 0; i < 2; ++i)
#pragma unroll
        for (int j = 0; j < NTW; ++j) acc[i][j] = (floatx4){0.f, 0.f, 0.f, 0.f};

    for (int k0 = 0; k0 < 768; k0 += 32) {
        // stage K-slice (C x 32) and Q-slice (64 x 32); chunk = 16B, 4 chunks/row
        constexpr int CH = C * 4;
        for (int c = t; c < CH; c += 512)
            async16(Ks + c * 8, Kb + (size_t)(c >> 2) * 768 + k0 + (c & 3) * 8);
        if (t < 256)
            async16(Qs + t * 8, Qb + (size_t)(t >> 2) * 768 + k0 + (t & 3) * 8);
        __syncthreads();

        short8 af[2], bf[NTW];
#pragma unroll
        for (int i = 0; i < 2; ++i)
            af[i] = *(const short8*)(Qs + (wr2 * 32 + i * 16 + lr) * 32 + lq * 8);
#pragma unroll
        for (int j = 0; j < NTW; ++j)
            bf[j] = *(const short8*)(Ks + ((wc * NTW + j) * 16 + lr) * 32 + lq * 8);
#pragma unroll
        for (int i = 0; i < 2; ++i)
#pragma unroll
            for (int j = 0; j < NTW; ++j)
                acc[i][j] = __builtin_amdgcn_mfma_f32_16x16x32_bf16(af[i], bf[j], acc[i][j], 0, 0, 0);
        __syncthreads();
    }

    // ---- bias + mask (in-register) ----
    const int Rm = R - 64, Cm = C - 64;
    float mval[NTW];
#pragma unroll
    for (int j = 0; j < NTW; ++j)
        mval[j] = mask[(size_t)b * C + (wc * NTW + j) * 16 + lr];

#pragma unroll
    for (int i = 0; i < 2; ++i) {
        const int mmb = m0 + wr2 * 32 + i * 16 + lq * 4;
#pragma unroll
        for (int j = 0; j < NTW; ++j) {
            const int n = (wc * NTW + j) * 16 + lr;
#pragma unroll
            for (int r2 = 0; r2 < 4; ++r2) {
                const int mm = mmb + r2;
                const bool allowed = (n < Cm) || ((mm >= Rm) && ((n - Cm) <= (mm - Rm)));
                const float am = allowed ? mval[j] : 0.f;
                acc[i][j][r2] = acc[i][j][r2] * 0.125f + (am - 1.f) * 10000.f;
            }
        }
    }

    // ---- row max: per-lane over j, 16-lane shfl reduce, then cross-wave via LDS ----
    float pmax[2][4];
#pragma unroll
    for (int i = 0; i < 2; ++i)
#pragma unroll
        for (int r2 = 0; r2 < 4; ++r2) {
            float m_ = -3.0e38f;
#pragma unroll
            for (int j = 0; j < NTW; ++j) m_ = fmaxf(m_, acc[i][j][r2]);
#pragma unroll
            for (int d = 1; d < 16; d <<= 1) m_ = fmaxf(m_, __shfl_xor(m_, d, 64));
            pmax[i][r2] = m_;
        }
    if (lr == 0) {
#pragma unroll
        for (int i = 0; i < 2; ++i)
#pragma unroll
            for (int r2 = 0; r2 < 4; ++r2)
                red[wc][wr2 * 32 + i * 16 + lq * 4 + r2] = pmax[i][r2];
    }
    __syncthreads();
#pragma unroll
    for (int i = 0; i < 2; ++i)
#pragma unroll
        for (int r2 = 0; r2 < 4; ++r2) {
            const int rr = wr2 * 32 + i * 16 + lq * 4 + r2;
            pmax[i][r2] = fmaxf(fmaxf(red[0][rr], red[1][rr]), fmaxf(red[2][rr], red[3][rr]));
        }
    __syncthreads();

    // ---- exp + row sum ----
    float psum[2][4];
#pragma unroll
    for (int i = 0; i < 2; ++i)
#pragma unroll
        for (int r2 = 0; r2 < 4; ++r2) {
            float s_ = 0.f;
#pragma unroll
            for (int j = 0; j < NTW; ++j) {
                const float e = __expf(acc[i][j][r2] - pmax[i][r2]);
                acc[i][j][r2] = e;
                s_ += e;
            }
#pragma unroll
            for (int d = 1; d < 16; d <<= 1) s_ += __shfl_xor(s_, d, 64);
            psum[i][r2] = s_;
        }
    if (lr == 0) {
#pragma unroll
        for (int i = 0; i < 2; ++i)
#pragma unroll
            for (int r2 = 0; r2 < 4; ++r2)
                red[wc][wr2 * 32 + i * 16 + lq * 4 + r2] = psum[i][r2];
    }
    __syncthreads();

    // ---- normalize + write P (bf16) ----
#pragma unroll
    for (int i = 0; i < 2; ++i)
#pragma unroll
        for (int r2 = 0; r2 < 4; ++r2) {
            const int rr = wr2 * 32 + i * 16 + lq * 4 + r2;
            const float inv = 1.f / (red[0][rr] + red[1][rr] + red[2][rr] + red[3][rr]);
            short* prow = Pb + (size_t)rr * C;
#pragma unroll
            for (int j = 0; j < NTW; ++j)
                prow[(wc * NTW + j) * 16 + lr] = f2bf(acc[i][j][r2] * inv);
        }
}

// ---------------- PV GEMM: O = P0 @ V0 + P1 @ V1 (fp32 out), V given transposed (768,C) ----
__global__ __launch_bounds__(256) void pv_gemm(
    const short* __restrict__ P0, const short* __restrict__ Vt0, int C0,
    const short* __restrict__ P1, const short* __restrict__ Vt1, int C1,
    float* __restrict__ O, int R)
{
    __shared__ short As[4096], Bs[4096];
    const int t = threadIdx.x, w = t >> 6, l = t & 63;
    const int wr = (w >> 1) * 64, wc = (w & 1) * 64, lr = l & 15, lq = l >> 4;
    const int b = blockIdx.z;
    const int m0 = blockIdx.x * 128, n0 = blockIdx.y * 128;

    floatx4 acc[4][4];
#pragma unroll
    for (int i = 0; i < 4; ++i)
#pragma unroll
        for (int j = 0; j < 4; ++j) acc[i][j] = (floatx4){0.f, 0.f, 0.f, 0.f};

    for (int s = 0; s < 2; ++s) {
        const short* Ab = (s ? P1 : P0);
        const short* Bb = (s ? Vt1 : Vt0);
        const int C = s ? C1 : C0;
        Ab += ((size_t)b * R + m0) * C;
        Bb += ((size_t)b * 768 + n0) * C;
        for (int k0 = 0; k0 < C; k0 += 32) {
            stage128x32(As, Ab + k0, C, t);
            stage128x32(Bs, Bb + k0, C, t);
            __syncthreads();
            short8 af[4], bf[4];
#pragma unroll
            for (int i = 0; i < 4; ++i) af[i] = *(const short8*)(As + (wr + i * 16 + lr) * 32 + lq * 8);
#pragma unroll
            for (int j = 0; j < 4; ++j) bf[j] = *(const short8*)(Bs + (wc + j * 16 + lr) * 32 + lq * 8);
#pragma unroll
            for (int i = 0; i < 4; ++i)
#pragma unroll
                for (int j = 0; j < 4; ++j)
                    acc[i][j] = __builtin_amdgcn_mfma_f32_16x16x32_bf16(af[i], bf[j], acc[i][j], 0, 0, 0);
            __syncthreads();
        }
    }

#pragma unroll
    for (int i = 0; i < 4; ++i) {
        const int mb = m0 + wr + i * 16 + lq * 4;
#pragma unroll
        for (int j = 0; j < 4; ++j) {
            const int n = n0 + wc + j * 16 + lr;
#pragma unroll
            for (int r2 = 0; r2 < 4; ++r2) {
                if (mb + r2 < R)
                    O[((size_t)b * R + mb + r2) * 768 + n] = acc[i][j][r2];
            }
        }
    }
}

// ---------------- host ----------------
extern "C" void kernel_launch(void* const* d_in, const int* in_sizes, int n_in,
                              void* d_out, int out_size, void* d_ws, size_t ws_size,
                              hipStream_t stream) {
    const float* vidX = (const float*)d_in[0];
    const float* mV   = (const float*)d_in[1];
    const float* detX = (const float*)d_in[2];
    const float* mD   = (const float*)d_in[3];
    const float* actX = (const float*)d_in[4];
    const float* mA   = (const float*)d_in[5];
    const float* Wv   = (const float*)d_in[6];
    const float* bv   = (const float*)d_in[7];
    const float* Wd   = (const float*)d_in[8];
    const float* bd   = (const float*)d_in[9];
    const float* Wa   = (const float*)d_in[10];
    const float* ba   = (const float*)d_in[11];

    const size_t EV = 28311552, ED = 15728640, EA = 9437184;   // elems per Y matrix
    char* p = (char*)d_ws;
    auto alloc = [&](size_t bytes) { char* r = p; p += (bytes + 255) & ~255ULL; return r; };

    short* Wvb = (short*)alloc(589824 * 2);
    short* Wdb = (short*)alloc(589824 * 2);
    short* Wab = (short*)alloc(589824 * 2);
    short* Yv  = (short*)alloc(EV * 2);
    short* Yd  = (short*)alloc(ED * 2);
    short* Ya  = (short*)alloc(EA * 2);
    short* Ytv = (short*)alloc(EV * 2);
    short* Ytd = (short*)alloc(ED * 2);
    short* Yta = (short*)alloc(EA * 2);
    // X bf16 region (inputs cast once; no longer reused for S — S stays in registers)
    char* xs  = alloc((EV + ED + EA) * 2);
    short* Xv = (short*)xs;
    short* Xd = Xv + EV;
    short* Xa = Xd + ED;
    short* Pvd = (short*)alloc((size_t)64 * 576 * 320 * 2);
    short* Pva = (short*)alloc((size_t)64 * 576 * 192 * 2);
    short* Pdv = (short*)alloc((size_t)64 * 320 * 576 * 2);
    short* Pda = (short*)alloc((size_t)64 * 320 * 192 * 2);
    short* Pav = (short*)alloc((size_t)64 * 192 * 576 * 2);
    short* Pad = (short*)alloc((size_t)64 * 192 * 320 * 2);
    (void)alloc(262144);   // slack for guarded-tile overhang reads

    float* o0 = (float*)d_out;
    float* o1 = o0 + EV;
    float* o2 = o1 + ED;

    // casts
    cast_kernel<<<576, 256, 0, stream>>>(Wv, Wvb, 147456);
    cast_kernel<<<576, 256, 0, stream>>>(Wd, Wdb, 147456);
    cast_kernel<<<576, 256, 0, stream>>>(Wa, Wab, 147456);
    cast_kernel<<<27648, 256, 0, stream>>>(vidX, Xv, (int)(EV / 4));
    cast_kernel<<<15360, 256, 0, stream>>>(detX, Xd, (int)(ED / 4));
    cast_kernel<<<9216, 256, 0, stream>>>(actX, Xa, (int)(EA / 4));

    // projections (M = 64*L, all exact multiples of 128)
    proj_gemm<<<dim3(288, 6), 256, 0, stream>>>(Xv, Wvb, bv, Yv, Ytv, 576);
    proj_gemm<<<dim3(160, 6), 256, 0, stream>>>(Xd, Wdb, bd, Yd, Ytd, 320);
    proj_gemm<<<dim3(96, 6), 256, 0, stream>>>(Xa, Wab, ba, Ya, Yta, 192);

    // fused S+softmax, one launch per shared-K group (pairs packed in blockIdx.y)
    fused_sp<576><<<dim3(5, 2, 64), 512, 0, stream>>>(Yv, mV, Yd, 320, Pdv, Ya, 192, Pav);
    fused_sp<320><<<dim3(9, 2, 64), 512, 0, stream>>>(Yd, mD, Yv, 576, Pvd, Ya, 192, Pad);
    fused_sp<192><<<dim3(9, 2, 64), 512, 0, stream>>>(Ya, mA, Yv, 576, Pva, Yd, 320, Pda);

    // PV GEMMs (two sources accumulated)
    pv_gemm<<<dim3(5, 6, 64), 256, 0, stream>>>(Pvd, Ytd, 320, Pva, Yta, 192, o0, 576);
    pv_gemm<<<dim3(3, 6, 64), 256, 0, stream>>>(Pdv, Ytv, 576, Pda, Yta, 192, o1, 320);
    pv_gemm<<<dim3(2, 6, 64), 256, 0, stream>>>(Pav, Ytv, 576, Pad, Ytd, 320, o2, 192);
}